// Round 5
// baseline (539.358 us; speedup 1.0000x reference)
//
#include <hip/hip_runtime.h>

// MaskedAttention: B=4,S=1024,W=1024,H=16,DH=64. Softmax over HEAD axis.
// cvt->bf16; QKV GEMM (m97-style global_load_lds staging, V stored [d][s]);
// qksm: QK^T + in-reg 16-way head softmax, P transposed through LDS and
// stored as full 128B lines into plain [b][h][q][k] layout; pv: batched
// P@V GEMM; out-proj GEMM. P in two q-halves (pws 64MB reused), ws 112MB.

typedef float f32x4 __attribute__((ext_vector_type(4)));
typedef __bf16 bf16x8 __attribute__((ext_vector_type(8)));

__device__ __forceinline__ unsigned short f2bf(float f){
  unsigned int u = __builtin_bit_cast(unsigned int, f);
  u = (u + 0x7FFFu + ((u >> 16) & 1u)) >> 16;
  return (unsigned short)u;
}

// async global->LDS, 16B per lane; LDS dest = wave-uniform base + lane*16
__device__ __forceinline__ void gl16(const unsigned short* g, unsigned short* l){
  __builtin_amdgcn_global_load_lds(
      (const __attribute__((address_space(1))) void*)g,
      (__attribute__((address_space(3))) void*)l, 16, 0, 0);
}

__global__ __launch_bounds__(256) void cvt_kernel(const float* __restrict__ s,
                                                  unsigned short* __restrict__ d, int n4){
  int i = blockIdx.x * 256 + threadIdx.x;
  if (i < n4){
    float4 v = ((const float4*)s)[i];
    ushort4 o;
    o.x = f2bf(v.x); o.y = f2bf(v.y); o.z = f2bf(v.z); o.w = f2bf(v.w);
    ((ushort4*)d)[i] = o;
  }
}

__global__ __launch_bounds__(256) void cvt4_kernel(
    const float* __restrict__ s0, const float* __restrict__ s1,
    const float* __restrict__ s2, const float* __restrict__ s3,
    unsigned short* __restrict__ d0, unsigned short* __restrict__ d1,
    unsigned short* __restrict__ d2, unsigned short* __restrict__ d3){
  int i = blockIdx.x * 256 + threadIdx.x;
  int seg = i >> 18, j = i & 262143;
  const float* s = (seg == 0) ? s0 : (seg == 1) ? s1 : (seg == 2) ? s2 : s3;
  unsigned short* d = (seg == 0) ? d0 : (seg == 1) ? d1 : (seg == 2) ? d2 : d3;
  float4 v = ((const float4*)s)[j];
  ushort4 o;
  o.x = f2bf(v.x); o.y = f2bf(v.y); o.z = f2bf(v.z); o.w = f2bf(v.w);
  ((ushort4*)d)[j] = o;
}

// ---------------- GEMM: C[m,n] = sum_k A[m,k]*Wt[n,k] (+bias) -----------------
template<int MODE>
__global__ __launch_bounds__(256) void gemm_bt(
    const unsigned short* __restrict__ A, const unsigned short* __restrict__ Wt,
    int M, int N, int K,
    float* __restrict__ outp,
    unsigned short* __restrict__ qws, unsigned short* __restrict__ kws,
    unsigned short* __restrict__ vws,
    const float* __restrict__ bias0, const float* __restrict__ bias1,
    const float* __restrict__ bias2)
{
  __shared__ unsigned short As_[128*32];
  __shared__ unsigned short Bs_[128*32];
  const int tid = threadIdx.x;
  const int lane = tid & 63;
  const int wid = tid >> 6;
  const int wr = wid >> 1, wc = wid & 1;
  const int m0 = blockIdx.x * 128, n0 = blockIdx.y * 128;
  const int lq = lane & 15, lg = lane >> 4;
  const int srow = (wid << 5) + (lane >> 2);
  const int scol = (lane & 3) << 3;
  const unsigned short* Ag = A  + (size_t)(m0 + srow)*K + scol;
  const unsigned short* Bg = Wt + (size_t)(n0 + srow)*K + scol;
  char* a_l0 = (char*)As_ + (wid << 11);
  char* b_l0 = (char*)Bs_ + (wid << 11);
  f32x4 acc[4][4] = {};

  for (int k0 = 0; k0 < K; k0 += 32){
    gl16(Ag + k0,                 (unsigned short*)a_l0);
    gl16(Ag + (size_t)16*K + k0,  (unsigned short*)(a_l0 + 1024));
    gl16(Bg + k0,                 (unsigned short*)b_l0);
    gl16(Bg + (size_t)16*K + k0,  (unsigned short*)(b_l0 + 1024));
    __syncthreads();
    bf16x8 af[4], wf[4];
    #pragma unroll
    for (int i = 0; i < 4; ++i){
      af[i] = *(const bf16x8*)((char*)As_ + ((((wr<<6)+(i<<4)+lq)) << 6) + (lg << 4));
      wf[i] = *(const bf16x8*)((char*)Bs_ + ((((wc<<6)+(i<<4)+lq)) << 6) + (lg << 4));
    }
    #pragma unroll
    for (int i = 0; i < 4; ++i)
      #pragma unroll
      for (int j = 0; j < 4; ++j)
        acc[i][j] = __builtin_amdgcn_mfma_f32_16x16x32_bf16(af[i], wf[j], acc[i][j], 0, 0, 0);
    __syncthreads();
  }

  if (MODE == 0){
    #pragma unroll
    for (int j = 0; j < 4; ++j){
      int ncol = n0 + wc*64 + j*16 + lq;
      float bv = bias0[ncol];
      #pragma unroll
      for (int i = 0; i < 4; ++i){
        int mrow = m0 + wr*64 + i*16 + lg*4;
        #pragma unroll
        for (int r = 0; r < 4; ++r)
          outp[(size_t)(mrow + r)*N + ncol] = acc[i][j][r] + bv;
      }
    }
  } else {
    const int sel = n0 >> 10;   // uniform per block: 0=Q 1=K 2=V
    const float* bp = (sel == 0) ? bias0 : ((sel == 1) ? bias1 : bias2);
    #pragma unroll
    for (int j = 0; j < 4; ++j){
      int n  = n0 + wc*64 + j*16 + lq;
      int n1 = n & 1023;
      int h = n1 >> 6, d = n1 & 63;
      float bv = bp[n1];
      #pragma unroll
      for (int i = 0; i < 4; ++i){
        int mbase = m0 + wr*64 + i*16 + lg*4;
        #pragma unroll
        for (int r = 0; r < 4; ++r){
          int m = mbase + r;
          int b = m >> 10, s = m & 1023;
          unsigned short o = f2bf(acc[i][j][r] + bv);
          if (sel == 0)      qws[(size_t)((((b<<4) + h)<<10) + s)*64 + d] = o;
          else if (sel == 1) kws[(size_t)((((b<<4) + h)<<10) + s)*64 + d] = o;
          else               vws[(size_t)((((b<<4) + h)<<6) + d)*1024 + s] = o;
        }
      }
    }
  }
}

// ---------------- qksm: QK^T + head-softmax -> P [b][h][q512][k1024] ---------
// grid (kt=4, qt=32, b=4), 8 waves. Q/K frags straight from global (L2).
// Per it (128 k): wave w computes 16 k-cols x 16 heads, softmax in-reg,
// scatters bf16 P into LDS [2][16h][16q][64k] (XOR swz lg<<5), then all 512
// threads store the 64KB tile as uint4 -> full 128B lines, no partial-line RMW.
__global__ __launch_bounds__(512, 4) void qksm_kernel(
    const unsigned short* __restrict__ qws, const unsigned short* __restrict__ kws,
    const int* __restrict__ mask, unsigned short* __restrict__ pws, int qbase)
{
  __shared__ unsigned short Ps[32768];   // 64KB: [2][16h][16q][64k]
  const int tid = threadIdx.x;
  const int lane = tid & 63, w = tid >> 6;
  const int kt = blockIdx.x, qt = blockIdx.y, b = blockIdx.z;
  const int q0 = qbase + (qt << 4);
  const int lq = lane & 15, lg = lane >> 4;
  const int buf = w >> 2, ksub = w & 3;
  const float kscale = 0.125f * 1.44269504f;

  for (int it = 0; it < 2; ++it){
    const int kb = (kt << 8) + (it << 7) + (w << 4);   // wave's global k base
    // ---- QK^T: 16 heads x 16 k-cols; lane holds (q=lg*4+r, k=lq)
    f32x4 sc[16];
    #pragma unroll
    for (int h = 0; h < 16; ++h){
      const unsigned short* qp = qws + (size_t)((((b<<4)+h)<<10) + q0 + lq)*64 + (lg<<3);
      bf16x8 a0 = *(const bf16x8*)(qp);
      bf16x8 a1 = *(const bf16x8*)(qp + 32);
      const unsigned short* kp = kws + (size_t)((((b<<4)+h)<<10) + kb + lq)*64 + (lg<<3);
      bf16x8 kf0 = *(const bf16x8*)(kp);
      bf16x8 kf1 = *(const bf16x8*)(kp + 32);
      f32x4 s = {};
      s = __builtin_amdgcn_mfma_f32_16x16x32_bf16(a0, kf0, s, 0, 0, 0);
      s = __builtin_amdgcn_mfma_f32_16x16x32_bf16(a1, kf1, s, 0, 0, 0);
      sc[h] = s;
    }
    // ---- head-softmax + scatter into LDS tile
    const int* mp = mask + (size_t)((b<<10) + q0 + (lg<<2))*1024 + kb + lq;
    #pragma unroll
    for (int r = 0; r < 4; ++r){
      const int mv = mp[r << 10];
      float mx = sc[0][r];
      #pragma unroll
      for (int h = 1; h < 16; ++h) mx = fmaxf(mx, sc[h][r]);
      float e[16]; float sum = 0.f;
      #pragma unroll
      for (int h = 0; h < 16; ++h){
        e[h] = __builtin_amdgcn_exp2f((sc[h][r] - mx) * kscale);
        sum += e[h];
      }
      const float rs = __builtin_amdgcn_rcpf(sum);
      const int q = (lg << 2) + r;
      const int base = (buf << 15) | (q << 7) | (((ksub << 4) | lq) << 1);
      const int swz = lg << 5;
      #pragma unroll
      for (int h = 0; h < 16; ++h){
        float pv = mv ? (e[h] * rs) : 0.0625f;   // all heads masked => exactly 1/16
        *(unsigned short*)((char*)Ps + ((base | (h << 11)) ^ swz)) = f2bf(pv);
      }
    }
    __syncthreads();
    // ---- cooperative coalesced store: 64KB tile -> pws[b][h][q512][k1024]
    #pragma unroll
    for (int j = 0; j < 8; ++j){
      int e = ((j << 9) + tid) << 3;               // element index in tile
      int bufr = e >> 14, h = (e >> 10) & 15, q = (e >> 6) & 15, k64 = e & 63;
      int lbyte = (e << 1) ^ (((q >> 2) & 3) << 5);
      uint4 v = *(const uint4*)((const char*)Ps + lbyte);
      size_t go = ((size_t)b << 23) + ((size_t)h << 19) + ((size_t)((qt << 4) | q) << 10)
                + (kt << 8) + (it << 7) + (bufr << 6) + k64;
      *(uint4*)(pws + go) = v;
    }
    __syncthreads();
  }
}

// ---------------- pv: x[q][h*64+d] = sum_k P[q,k]*V[d,k], batched (b,h) ------
// grid (qt=4, bh=64), 4 waves (each 32q x 64d). m97-style staging.
__global__ __launch_bounds__(256) void pv_kernel(
    const unsigned short* __restrict__ pws, const unsigned short* __restrict__ vws,
    unsigned short* __restrict__ xbf, int qbase)
{
  __shared__ unsigned short Ps_[128*32];
  __shared__ unsigned short Vs_[64*32];
  const int tid = threadIdx.x;
  const int lane = tid & 63;
  const int wid = tid >> 6;
  const int qt = blockIdx.x, bh = blockIdx.y;
  const int b = bh >> 4, h = bh & 15;
  const int lq = lane & 15, lg = lane >> 4;
  const int arow = (wid << 5) + (lane >> 2);
  const int scol = (lane & 3) << 3;
  const unsigned short* Ag = pws + ((size_t)bh << 19) + ((size_t)((qt << 7) + arow) << 10) + scol;
  const int brow = (wid << 4) + (lane >> 2);
  const unsigned short* Bg = vws + ((size_t)bh << 16) + brow*1024 + scol;
  char* a_l0 = (char*)Ps_ + (wid << 11);
  char* b_l0 = (char*)Vs_ + (wid << 10);
  f32x4 acc[2][4] = {};

  for (int k0 = 0; k0 < 1024; k0 += 32){
    gl16(Ag + k0,             (unsigned short*)a_l0);
    gl16(Ag + k0 + (16 << 10),(unsigned short*)(a_l0 + 1024));
    gl16(Bg + k0,             (unsigned short*)b_l0);
    __syncthreads();
    bf16x8 af[2], wf[4];
    #pragma unroll
    for (int i = 0; i < 2; ++i)
      af[i] = *(const bf16x8*)((char*)Ps_ + ((((wid<<5)+(i<<4)+lq)) << 6) + (lg << 4));
    #pragma unroll
    for (int j = 0; j < 4; ++j)
      wf[j] = *(const bf16x8*)((char*)Vs_ + ((((j<<4)+lq)) << 6) + (lg << 4));
    #pragma unroll
    for (int i = 0; i < 2; ++i)
      #pragma unroll
      for (int j = 0; j < 4; ++j)
        acc[i][j] = __builtin_amdgcn_mfma_f32_16x16x32_bf16(af[i], wf[j], acc[i][j], 0, 0, 0);
    __syncthreads();
  }

  #pragma unroll
  for (int j = 0; j < 4; ++j){
    int d = (j << 4) + lq;
    #pragma unroll
    for (int i = 0; i < 2; ++i){
      #pragma unroll
      for (int r = 0; r < 4; ++r){
        int qrow = qbase + (qt << 7) + (wid << 5) + (i << 4) + (lg << 2) + r;
        xbf[(size_t)((b << 10) + qrow)*1024 + (h << 6) + d] = f2bf(acc[i][j][r]);
      }
    }
  }
}

extern "C" void kernel_launch(void* const* d_in, const int* in_sizes, int n_in,
                              void* d_out, int out_size, void* d_ws, size_t ws_size,
                              hipStream_t stream) {
  const float* inp = (const float*)d_in[0];
  const int*  mask = (const int*)d_in[1];
  const float* wq = (const float*)d_in[2];
  const float* bq = (const float*)d_in[3];
  const float* wk = (const float*)d_in[4];
  const float* bk = (const float*)d_in[5];
  const float* wv = (const float*)d_in[6];
  const float* bv = (const float*)d_in[7];
  const float* wo = (const float*)d_in[8];
  const float* bo = (const float*)d_in[9];
  float* out = (float*)d_out;

  char* ws = (char*)d_ws;
  unsigned short* inp_bf = (unsigned short*)(ws);                    // 8MB
  unsigned short* wqkv   = (unsigned short*)(ws + (8u  << 20));      // 6MB
  unsigned short* wo_bf  = (unsigned short*)(ws + (14u << 20));      // 2MB
  unsigned short* qws    = (unsigned short*)(ws + (16u << 20));      // 8MB [b][h][s][d]
  unsigned short* kws    = (unsigned short*)(ws + (24u << 20));      // 8MB [b][h][s][d]
  unsigned short* vws    = (unsigned short*)(ws + (32u << 20));      // 8MB [b][h][d][s]
  unsigned short* xbf    = (unsigned short*)(ws + (40u << 20));      // 8MB
  unsigned short* pws    = (unsigned short*)(ws + (48u << 20));      // 64MB [b][h][q512][k1024]

  cvt_kernel<<<4096, 256, 0, stream>>>(inp, inp_bf, 1048576);
  cvt4_kernel<<<4096, 256, 0, stream>>>(wq, wk, wv, wo,
                                        wqkv, wqkv + (1u << 20), wqkv + (2u << 20), wo_bf);

  gemm_bt<1><<<dim3(32, 24), 256, 0, stream>>>(inp_bf, wqkv, 4096, 3072, 1024,
                                               nullptr, qws, kws, vws, bq, bk, bv);

  for (int half = 0; half < 2; ++half){
    qksm_kernel<<<dim3(4, 32, 4), 512, 0, stream>>>(qws, kws, mask, pws, half * 512);
    pv_kernel<<<dim3(4, 64), 256, 0, stream>>>(pws, vws, xbf, half * 512);
  }

  gemm_bt<0><<<dim3(32, 8), 256, 0, stream>>>(xbf, wo_bf, 4096, 1024, 1024,
                                              out, nullptr, nullptr, nullptr, bo, nullptr, nullptr);
}

// Round 7
// 482.238 us; speedup vs baseline: 1.1184x; 1.1184x over previous
//
#include <hip/hip_runtime.h>

// MaskedAttention: B=4,S=1024,W=1024,H=16,DH=64. Softmax over HEAD axis.
// cvt->bf16; QKV GEMM (Q/K -> [b][h][s][d] bf16, V -> plain rows);
// vt: V -> bf16 [b][h][d][k]; qksm: QK^T + in-reg 16-way head softmax ->
// P bf16 [b][q][k][h16] (two uint4 stores per (q,k); full-line writes,
// no LDS, no barriers); pv: bf16 MFMA P@V, P frags direct from global (L2),
// 8 heads/block; out-proj GEMM. P in two q-halves, ws <= 104MB.

typedef float f32x4 __attribute__((ext_vector_type(4)));
typedef __bf16 bf16x8 __attribute__((ext_vector_type(8)));

__device__ __forceinline__ unsigned short f2bf(float f){
  unsigned int u = __builtin_bit_cast(unsigned int, f);
  u = (u + 0x7FFFu + ((u >> 16) & 1u)) >> 16;
  return (unsigned short)u;
}

// async global->LDS, 16B per lane
__device__ __forceinline__ void gl16(const unsigned short* g, unsigned short* l){
  __builtin_amdgcn_global_load_lds(
      (const __attribute__((address_space(1))) void*)g,
      (__attribute__((address_space(3))) void*)l, 16, 0, 0);
}

__global__ __launch_bounds__(256) void cvt_kernel(const float* __restrict__ s,
                                                  unsigned short* __restrict__ d, int n4){
  int i = blockIdx.x * 256 + threadIdx.x;
  if (i < n4){
    float4 v = ((const float4*)s)[i];
    ushort4 o;
    o.x = f2bf(v.x); o.y = f2bf(v.y); o.z = f2bf(v.z); o.w = f2bf(v.w);
    ((ushort4*)d)[i] = o;
  }
}

__global__ __launch_bounds__(256) void cvt4_kernel(
    const float* __restrict__ s0, const float* __restrict__ s1,
    const float* __restrict__ s2, const float* __restrict__ s3,
    unsigned short* __restrict__ d0, unsigned short* __restrict__ d1,
    unsigned short* __restrict__ d2, unsigned short* __restrict__ d3){
  int i = blockIdx.x * 256 + threadIdx.x;
  int seg = i >> 18, j = i & 262143;
  const float* s = (seg == 0) ? s0 : (seg == 1) ? s1 : (seg == 2) ? s2 : s3;
  unsigned short* d = (seg == 0) ? d0 : (seg == 1) ? d1 : (seg == 2) ? d2 : d3;
  float4 v = ((const float4*)s)[j];
  ushort4 o;
  o.x = f2bf(v.x); o.y = f2bf(v.y); o.z = f2bf(v.z); o.w = f2bf(v.w);
  ((ushort4*)d)[j] = o;
}

// ---------------- GEMM: C[m,n] = sum_k A[m,k]*Wt[n,k] (+bias) -----------------
// MODE 0: outp f32 [M][N]. MODE 1: Q/K -> [b][h][s][d] bf16, V -> vrow plain bf16.
template<int MODE>
__global__ __launch_bounds__(256) void gemm_bt(
    const unsigned short* __restrict__ A, const unsigned short* __restrict__ Wt,
    int M, int N, int K,
    float* __restrict__ outp,
    unsigned short* __restrict__ qws, unsigned short* __restrict__ kws,
    unsigned short* __restrict__ vrow,
    const float* __restrict__ bias0, const float* __restrict__ bias1,
    const float* __restrict__ bias2)
{
  __shared__ unsigned short As_[128*32];
  __shared__ unsigned short Bs_[128*32];
  const int tid = threadIdx.x;
  const int lane = tid & 63;
  const int wid = tid >> 6;
  const int wr = wid >> 1, wc = wid & 1;
  const int m0 = blockIdx.x * 128, n0 = blockIdx.y * 128;
  const int lq = lane & 15, lg = lane >> 4;
  const int srow = (wid << 5) + (lane >> 2);
  const int scol = (lane & 3) << 3;
  const unsigned short* Ag = A  + (size_t)(m0 + srow)*K + scol;
  const unsigned short* Bg = Wt + (size_t)(n0 + srow)*K + scol;
  char* a_l0 = (char*)As_ + (wid << 11);
  char* b_l0 = (char*)Bs_ + (wid << 11);
  f32x4 acc[4][4] = {};

  for (int k0 = 0; k0 < K; k0 += 32){
    gl16(Ag + k0,                 (unsigned short*)a_l0);
    gl16(Ag + (size_t)16*K + k0,  (unsigned short*)(a_l0 + 1024));
    gl16(Bg + k0,                 (unsigned short*)b_l0);
    gl16(Bg + (size_t)16*K + k0,  (unsigned short*)(b_l0 + 1024));
    __syncthreads();
    bf16x8 af[4], wf[4];
    #pragma unroll
    for (int i = 0; i < 4; ++i){
      af[i] = *(const bf16x8*)((char*)As_ + ((((wr<<6)+(i<<4)+lq)) << 6) + (lg << 4));
      wf[i] = *(const bf16x8*)((char*)Bs_ + ((((wc<<6)+(i<<4)+lq)) << 6) + (lg << 4));
    }
    #pragma unroll
    for (int i = 0; i < 4; ++i)
      #pragma unroll
      for (int j = 0; j < 4; ++j)
        acc[i][j] = __builtin_amdgcn_mfma_f32_16x16x32_bf16(af[i], wf[j], acc[i][j], 0, 0, 0);
    __syncthreads();
  }

  if (MODE == 0){
    #pragma unroll
    for (int j = 0; j < 4; ++j){
      int ncol = n0 + wc*64 + j*16 + lq;
      float bv = bias0[ncol];
      #pragma unroll
      for (int i = 0; i < 4; ++i){
        int mrow = m0 + wr*64 + i*16 + lg*4;
        #pragma unroll
        for (int r = 0; r < 4; ++r)
          outp[(size_t)(mrow + r)*N + ncol] = acc[i][j][r] + bv;
      }
    }
  } else {
    const int sel = n0 >> 10;   // uniform per block: 0=Q 1=K 2=V
    const float* bp = (sel == 0) ? bias0 : ((sel == 1) ? bias1 : bias2);
    #pragma unroll
    for (int j = 0; j < 4; ++j){
      int n  = n0 + wc*64 + j*16 + lq;
      int n1 = n & 1023;
      int h = n1 >> 6, d = n1 & 63;
      float bv = bp[n1];
      #pragma unroll
      for (int i = 0; i < 4; ++i){
        int mbase = m0 + wr*64 + i*16 + lg*4;
        #pragma unroll
        for (int r = 0; r < 4; ++r){
          int m = mbase + r;
          int b = m >> 10, s = m & 1023;
          unsigned short o = f2bf(acc[i][j][r] + bv);
          if (sel == 0)      qws[(size_t)((((b<<4) + h)<<10) + s)*64 + d] = o;
          else if (sel == 1) kws[(size_t)((((b<<4) + h)<<10) + s)*64 + d] = o;
          else               vrow[(size_t)m*1024 + n1] = o;
        }
      }
    }
  }
}

// ---------------- vt: vrow [b][s][h][d] bf16 -> vws [b][h][d][k=s] bf16 ------
// grid (st=8, bh=64), 256 thr. 128s x 64d tile via LDS (stride 72).
__global__ __launch_bounds__(256) void vt_kernel(const unsigned short* __restrict__ vrow,
                                                 unsigned short* __restrict__ vws)
{
  __shared__ unsigned short T[128*72];
  const int tid = threadIdx.x;
  const int st = blockIdx.x, bh = blockIdx.y;
  const int b = bh >> 4, h = bh & 15;
  const int s0 = st << 7;
  const int sr = tid >> 1, dc = (tid & 1) << 5;
  const unsigned short* src = vrow + (size_t)((b<<10) + s0 + sr)*1024 + (h<<6) + dc;
  #pragma unroll
  for (int j = 0; j < 4; ++j)
    *(uint4*)(&T[sr*72 + dc + (j<<3)]) = *(const uint4*)(src + (j<<3));
  __syncthreads();
  const int d = tid >> 2, sc = (tid & 3) << 5;   // 32 consecutive s for one d
  unsigned int wds[16];
  #pragma unroll
  for (int m = 0; m < 16; ++m)
    wds[m] = (unsigned int)T[(sc + 2*m)*72 + d] | ((unsigned int)T[(sc + 2*m + 1)*72 + d] << 16);
  unsigned short* dst = vws + (((size_t)bh) << 16) + (d << 10) + s0 + sc;
  uint4 o0 = {wds[0],  wds[1],  wds[2],  wds[3]};
  uint4 o1 = {wds[4],  wds[5],  wds[6],  wds[7]};
  uint4 o2 = {wds[8],  wds[9],  wds[10], wds[11]};
  uint4 o3 = {wds[12], wds[13], wds[14], wds[15]};
  *(uint4*)(dst)      = o0;
  *(uint4*)(dst + 8)  = o1;
  *(uint4*)(dst + 16) = o2;
  *(uint4*)(dst + 24) = o3;
}

// ---------------- qksm: QK^T + head-softmax -> P bf16 [b][q512][k1024][h16] --
// 512 blocks/half: g=(kt,b)=bid&15 (XCD-pins K slice: bid%8 const per g),
// qt=bid>>4. 8 waves, NO LDS, NO barriers. Wave w: k-chunks kt*256+it*128+w*16.
// Per (q,k): 16 head P-values = 32B -> two uint4 stores (full-line coverage).
__global__ __launch_bounds__(512) void qksm_kernel(
    const unsigned short* __restrict__ qws, const unsigned short* __restrict__ kws,
    const int* __restrict__ mask, unsigned short* __restrict__ pws, int qbase)
{
  const int tid = threadIdx.x;
  const int lane = tid & 63, w = tid >> 6;
  const int bid = blockIdx.x;
  const int g = bid & 15, kt = g & 3, b = g >> 2, qt = bid >> 4;
  const int q0 = qbase + (qt << 4);
  const int lq = lane & 15, lg = lane >> 4;
  const float kscale = 0.125f * 1.44269504f;

  for (int it = 0; it < 2; ++it){
    const int kb = (kt << 8) + (it << 7) + (w << 4);
    // ---- QK^T: 16 heads x 16 k-cols; lane holds (q=4lg+r, k=lq)
    f32x4 sc[16];
    #pragma unroll
    for (int h = 0; h < 16; ++h){
      const unsigned short* qp = qws + (size_t)((((b<<4)+h)<<10) + q0 + lq)*64 + (lg<<3);
      const unsigned short* kp = kws + (size_t)((((b<<4)+h)<<10) + kb + lq)*64 + (lg<<3);
      bf16x8 a0 = *(const bf16x8*)(qp);
      bf16x8 a1 = *(const bf16x8*)(qp + 32);
      bf16x8 k0 = *(const bf16x8*)(kp);
      bf16x8 k1 = *(const bf16x8*)(kp + 32);
      f32x4 s = {};
      s = __builtin_amdgcn_mfma_f32_16x16x32_bf16(a0, k0, s, 0, 0, 0);
      s = __builtin_amdgcn_mfma_f32_16x16x32_bf16(a1, k1, s, 0, 0, 0);
      sc[h] = s;
    }
    // ---- head-softmax + bf16 pack + two uint4 stores per (q,k)
    const int* mp = mask + (size_t)((b<<10) + q0 + (lg<<2))*1024 + kb + lq;
    #pragma unroll
    for (int r = 0; r < 4; ++r){
      const int mv = mp[r << 10];
      float mx = sc[0][r];
      #pragma unroll
      for (int h = 1; h < 16; ++h) mx = fmaxf(mx, sc[h][r]);
      float e[16]; float sum = 0.f;
      #pragma unroll
      for (int h = 0; h < 16; ++h){
        e[h] = __builtin_amdgcn_exp2f((sc[h][r] - mx) * kscale);
        sum += e[h];
      }
      const float rs = __builtin_amdgcn_rcpf(sum);
      unsigned int wd[8];
      #pragma unroll
      for (int m = 0; m < 8; ++m){
        float p0 = mv ? (e[2*m]   * rs) : 0.0625f;
        float p1 = mv ? (e[2*m+1] * rs) : 0.0625f;
        wd[m] = (unsigned int)f2bf(p0) | ((unsigned int)f2bf(p1) << 16);
      }
      const int qloc = (qt << 4) + (lg << 2) + r;   // q within half
      char* pc = (char*)pws + (((size_t)((b << 9) + qloc)) << 15) + ((size_t)(kb + lq) << 5);
      uint4 lo = {wd[0], wd[1], wd[2], wd[3]};
      uint4 hi = {wd[4], wd[5], wd[6], wd[7]};
      *(uint4*)(pc)      = lo;
      *(uint4*)(pc + 16) = hi;
    }
  }
}

// ---------------- pv: x[q][h*64+d] = sum_k P[q,k,h] * V[h,d,k] (bf16 MFMA) ---
// grid 256/half: b=bid&3 (XCD-pins V), qt=(bid>>2)&31, hg=bid>>7. 512 thr,
// 8 waves = 8 heads (hg selects half of heads). No LDS; P frags via u16 from
// global (each 32B unit consumed fully by the 16 head-waves of the q-tile).
__global__ __launch_bounds__(512) void pv_kernel(
    const unsigned short* __restrict__ pws, const unsigned short* __restrict__ vws,
    unsigned short* __restrict__ xbf, int qbase)
{
  const int tid = threadIdx.x;
  const int lane = tid & 63;
  const int h = (blockIdx.x >> 7 << 3) + (tid >> 6);
  const int b = blockIdx.x & 3, qt = (blockIdx.x >> 2) & 31;
  const int lq = lane & 15, lg = lane >> 4;
  const unsigned short* prow = pws + (((size_t)((b << 9) + (qt << 4) + lq)) << 14) + h;
  const unsigned short* vp = vws + (((size_t)((b << 4) + h)) << 16);
  f32x4 acc[4] = {};

  for (int ks = 0; ks < 1024; ks += 32){
    const unsigned short* pk = prow + ((ks + (lg << 3)) << 4);
    union { bf16x8 v; unsigned short s[8]; } a;
    #pragma unroll
    for (int j = 0; j < 8; ++j) a.s[j] = pk[j << 4];
    #pragma unroll
    for (int j = 0; j < 4; ++j){
      bf16x8 wf = *(const bf16x8*)(vp + (size_t)((j << 4) + lq)*1024 + ks + (lg << 3));
      acc[j] = __builtin_amdgcn_mfma_f32_16x16x32_bf16(a.v, wf, acc[j], 0, 0, 0);
    }
  }

  #pragma unroll
  for (int j = 0; j < 4; ++j)
    #pragma unroll
    for (int r = 0; r < 4; ++r)
      xbf[(size_t)((b << 10) + qbase + (qt << 4) + (lg << 2) + r)*1024 + (h << 6) + (j << 4) + lq]
          = f2bf(acc[j][r]);
}

extern "C" void kernel_launch(void* const* d_in, const int* in_sizes, int n_in,
                              void* d_out, int out_size, void* d_ws, size_t ws_size,
                              hipStream_t stream) {
  const float* inp = (const float*)d_in[0];
  const int*  mask = (const int*)d_in[1];
  const float* wq = (const float*)d_in[2];
  const float* bq = (const float*)d_in[3];
  const float* wk = (const float*)d_in[4];
  const float* bk = (const float*)d_in[5];
  const float* wv = (const float*)d_in[6];
  const float* bv = (const float*)d_in[7];
  const float* wo = (const float*)d_in[8];
  const float* bo = (const float*)d_in[9];
  float* out = (float*)d_out;

  char* ws = (char*)d_ws;
  unsigned short* inp_bf = (unsigned short*)(ws);                    // 0-8MB (dead after gemm<1>)
  unsigned short* xbf    = (unsigned short*)(ws);                    // 0-8MB (written by pv, after inp_bf dead)
  unsigned short* wqkv   = (unsigned short*)(ws + (8u  << 20));      // 8-14MB
  unsigned short* wo_bf  = (unsigned short*)(ws + (14u << 20));      // 14-16MB
  unsigned short* qws    = (unsigned short*)(ws + (16u << 20));      // 16-24MB [b][h][s][d] bf16
  unsigned short* kws    = (unsigned short*)(ws + (24u << 20));      // 24-32MB [b][h][s][d] bf16
  unsigned short* vws    = (unsigned short*)(ws + (32u << 20));      // 32-40MB [b][h][d][k] bf16
  unsigned short* vrow   = (unsigned short*)(ws + (40u << 20));      // 40-48MB (dead after vt)
  unsigned short* pws    = (unsigned short*)(ws + (40u << 20));      // 40-104MB [b][q512][k][h16] bf16

  cvt_kernel<<<4096, 256, 0, stream>>>(inp, inp_bf, 1048576);
  cvt4_kernel<<<4096, 256, 0, stream>>>(wq, wk, wv, wo,
                                        wqkv, wqkv + (1u << 20), wqkv + (2u << 20), wo_bf);

  gemm_bt<1><<<dim3(32, 24), 256, 0, stream>>>(inp_bf, wqkv, 4096, 3072, 1024,
                                               nullptr, qws, kws, vrow, bq, bk, bv);

  vt_kernel<<<dim3(8, 64), 256, 0, stream>>>(vrow, vws);

  for (int half = 0; half < 2; ++half){
    qksm_kernel<<<512, 512, 0, stream>>>(qws, kws, mask, pws, half * 512);
    pv_kernel<<<256, 512, 0, stream>>>(pws, vws, xbf, half * 512);
  }

  gemm_bt<0><<<dim3(32, 8), 256, 0, stream>>>(xbf, wo_bf, 4096, 1024, 1024,
                                              out, nullptr, nullptr, nullptr, bo, nullptr, nullptr);
}